// Round 1
// 791.227 us; speedup vs baseline: 1.4158x; 1.4158x over previous
//
#include <hip/hip_runtime.h>
#include <math.h>

#define BTOK 16384
#define DDIM 1024
#define HDIM 4096
#define NEXP 8
#define MAXT 136    // gemm1 m-tiles (BM=128): <= 128 + 8 partials
#define MAXT2 96    // gemm2 m-tiles (BM=192): <= 93, padded to mult of 8

typedef float f32x4 __attribute__((ext_vector_type(4)));
typedef short short8 __attribute__((ext_vector_type(8)));

__device__ __forceinline__ unsigned int bf16r(float f) {
  unsigned int u = __float_as_uint(f);
  return (u + 0x7fffu + ((u >> 16) & 1u)) >> 16;  // RTN-even
}
__device__ __forceinline__ unsigned int pack2(float a, float b) {
  return bf16r(a) | (bf16r(b) << 16);
}
// tanh-GELU via exp: x*(1 - 1/(1+e^{2t})), t = sqrt(2/pi)(x+0.044715x^3)
__device__ __forceinline__ float gelu_fast(float x) {
  float t = 0.7978845608028654f * x * (1.0f + 0.044715f * x * x);
  float e = __expf(2.0f * t);
  return x * (1.0f - __builtin_amdgcn_rcpf(e + 1.0f));
}
// async global->LDS, 16B per lane; LDS dest must be uniform base + lane*16
__device__ __forceinline__ void gload16(const void* g, void* l) {
  __builtin_amdgcn_global_load_lds(
      (const __attribute__((address_space(1))) unsigned int*)g,
      (__attribute__((address_space(3))) unsigned int*)l, 16, 0, 0);
}

// ---------------- gating: fp64 logits, softmax, argmax; also emits x in bf16 ----------------
__global__ __launch_bounds__(256) void gate_kernel(
    const float* __restrict__ x, const float* __restrict__ Wg,
    float* __restrict__ gate_out, float* __restrict__ texp_out,
    float* __restrict__ tscore, int* __restrict__ expert_ws,
    unsigned short* __restrict__ xbf) {
  int wid = threadIdx.x >> 6, lane = threadIdx.x & 63;
  int b = blockIdx.x * 4 + wid;
  const float* xr = x + (size_t)b * DDIM;
  unsigned short* xbr = xbf + (size_t)b * DDIM;
  double acc[8];
#pragma unroll
  for (int e = 0; e < 8; ++e) acc[e] = 0.0;
#pragma unroll
  for (int i = 0; i < 4; ++i) {
    int d0 = (i * 64 + lane) * 4;
    float4 v = *(const float4*)(xr + d0);
    uint2 o;
    o.x = pack2(v.x, v.y);
    o.y = pack2(v.z, v.w);
    *(uint2*)(xbr + d0) = o;  // fused x -> bf16 conversion
    const float4* wp = (const float4*)(Wg + (size_t)d0 * 8);
    float xs[4] = {v.x, v.y, v.z, v.w};
#pragma unroll
    for (int j = 0; j < 4; ++j) {
      float4 w0 = wp[2 * j], w1 = wp[2 * j + 1];
      double xv = (double)xs[j];
      acc[0] += xv * (double)w0.x;
      acc[1] += xv * (double)w0.y;
      acc[2] += xv * (double)w0.z;
      acc[3] += xv * (double)w0.w;
      acc[4] += xv * (double)w1.x;
      acc[5] += xv * (double)w1.y;
      acc[6] += xv * (double)w1.z;
      acc[7] += xv * (double)w1.w;
    }
  }
#pragma unroll
  for (int off = 32; off > 0; off >>= 1) {
#pragma unroll
    for (int e = 0; e < 8; ++e) acc[e] += __shfl_down(acc[e], off, 64);
  }
  if (lane == 0) {
    double mx = acc[0];
#pragma unroll
    for (int e = 1; e < 8; ++e) mx = acc[e] > mx ? acc[e] : mx;
    double ex[8], s = 0.0;
#pragma unroll
    for (int e = 0; e < 8; ++e) { ex[e] = exp(acc[e] - mx); s += ex[e]; }
    int best = 0;
#pragma unroll
    for (int e = 1; e < 8; ++e) if (acc[e] > acc[best]) best = e;  // first-max
    double inv = 1.0 / s;
#pragma unroll
    for (int e = 0; e < 8; ++e) gate_out[(size_t)b * 8 + e] = (float)(ex[e] * inv);
    texp_out[b] = (float)best;
    tscore[b] = (float)(ex[best] * inv);
    expert_ws[b] = best;
  }
}

// ---------------- plan: ballot histogram + offsets + tile worklists (1 block) ----------------
__global__ __launch_bounds__(1024) void plan_kernel(
    const int* __restrict__ expert_ws, int* __restrict__ counts,
    int* __restrict__ offsets, int* __restrict__ cursors,
    int* __restrict__ tile_e, int* __restrict__ tile_ms, int* __restrict__ total_tiles,
    int* __restrict__ tile2_e, int* __restrict__ tile2_ms, int* __restrict__ total_tiles2,
    float* __restrict__ dens_out) {
  __shared__ int wcnt[16][8];
  __shared__ int tot[8];
  int tid = threadIdx.x, lane = tid & 63, wid = tid >> 6;
  int cnt[8];
#pragma unroll
  for (int e = 0; e < 8; ++e) cnt[e] = 0;
  for (int i = 0; i < 16; ++i) {
    int e = expert_ws[wid * 1024 + i * 64 + lane];
#pragma unroll
    for (int ee = 0; ee < 8; ++ee) {
      unsigned long long m = __ballot(e == ee);
      cnt[ee] += __popcll(m);
    }
  }
  if (lane == 0) {
#pragma unroll
    for (int e = 0; e < 8; ++e) wcnt[wid][e] = cnt[e];
  }
  __syncthreads();
  if (tid < 8) {
    int s = 0;
    for (int w = 0; w < 16; ++w) s += wcnt[w][tid];
    tot[tid] = s;
    counts[tid] = s;
  }
  __syncthreads();
  if (tid == 0) {
    int off = 0, t1 = 0, t2 = 0;
    for (int e = 0; e < NEXP; ++e) {
      int c = tot[e];
      offsets[e] = off;
      cursors[e] = off;
      dens_out[e] = (float)c / (float)BTOK;
      for (int ms = 0; ms < c; ms += 128) { tile_e[t1] = e; tile_ms[t1] = ms; ++t1; }
      for (int ms = 0; ms < c; ms += 192) { tile2_e[t2] = e; tile2_ms[t2] = ms; ++t2; }
      off += c;
    }
    offsets[NEXP] = off;
    *total_tiles = t1;
    *total_tiles2 = t2;
  }
}

// ---------------- scatter: block-aggregated ranks, 8 atomics per block ----------------
__global__ __launch_bounds__(256) void scatter_kernel(
    const int* __restrict__ expert_ws, int* __restrict__ cursors,
    int* __restrict__ token_list) {
  __shared__ int wbase[4][8];
  __shared__ int bbase[8];
  int tid = threadIdx.x, lane = tid & 63, wid = tid >> 6;
  int b = blockIdx.x * 256 + tid;
  int e = expert_ws[b];
  unsigned long long mymask = 0;
  int wc[8];
#pragma unroll
  for (int ee = 0; ee < 8; ++ee) {
    unsigned long long m = __ballot(e == ee);
    wc[ee] = __popcll(m);
    if (ee == e) mymask = m;
  }
  int rank = __popcll(mymask & ((1ull << lane) - 1ull));
  if (lane == 0) {
#pragma unroll
    for (int ee = 0; ee < 8; ++ee) wbase[wid][ee] = wc[ee];
  }
  __syncthreads();
  if (tid < 8) {
    int s0 = wbase[0][tid], s1 = wbase[1][tid], s2 = wbase[2][tid], s3 = wbase[3][tid];
    int t = s0 + s1 + s2 + s3;
    bbase[tid] = atomicAdd(&cursors[tid], t);
    wbase[0][tid] = 0;
    wbase[1][tid] = s0;
    wbase[2][tid] = s0 + s1;
    wbase[3][tid] = s0 + s1 + s2;
  }
  __syncthreads();
  token_list[bbase[e] + wbase[wid][e] + rank] = b;
}

// ---------------- transpose + convert: in[z][R][C] fp32 -> out[z][C][R] bf16 ----------------
// v2: store TRANSPOSED into LDS (4 scalar u16 writes), read back with one b64.
// Bank swizzle s(c) = ((c>>4)&3)<<2 XORed into the row index: bijective within a
// column, preserves 4-halfword contiguity (s only touches bits 2..3), spreads the
// 16-lane write groups across 16 distinct banks.
__global__ __launch_bounds__(256) void transpose_cvt_kernel(
    const float* __restrict__ in, unsigned short* __restrict__ out, int R, int C) {
  __shared__ unsigned short tT[64 * 68];  // [col][row^swz], pad 68
  const float* ine = in + (size_t)blockIdx.z * R * C;
  unsigned short* oute = out + (size_t)blockIdx.z * R * C;
  int r0 = blockIdx.y * 64, c0 = blockIdx.x * 64;
  int tid = threadIdx.x;
#pragma unroll
  for (int l = 0; l < 4; ++l) {
    int f = tid + 256 * l;           // 0..1023
    int r = f >> 4, c4 = f & 15;     // row, float4-col
    float4 v = *(const float4*)(ine + (size_t)(r0 + r) * C + c0 + c4 * 4);
#pragma unroll
    for (int i = 0; i < 4; ++i) {
      int cc = 4 * c4 + i;
      int s = ((cc >> 4) & 3) << 2;
      float val = i == 0 ? v.x : (i == 1 ? v.y : (i == 2 ? v.z : v.w));
      tT[cc * 68 + (r ^ s)] = (unsigned short)bf16r(val);
    }
  }
  __syncthreads();
#pragma unroll
  for (int l = 0; l < 4; ++l) {
    int f = tid + 256 * l;           // 0..1023
    int oc = f >> 4, h4 = f & 15;    // out-row (=col), 4-row chunk
    int s = ((oc >> 4) & 3) << 2;
    uint2 o = *(const uint2*)(&tT[oc * 68 + ((4 * h4) ^ s)]);  // rows 4h4..4h4+3
    *(uint2*)(oute + (size_t)(c0 + oc) * R + r0 + 4 * h4) = o;
  }
}

// ---------------- GEMM1: h = gelu(x_gathered @ W1[e] + b1[e]) -> bf16 ----------------
// m97 structure + XOR bank swizzle, BM=128, + XCD-aware tile swizzle (136 = 8*17).
__global__ __launch_bounds__(256, 4) void gemm1_kernel(
    const unsigned short* __restrict__ xbf, const unsigned short* __restrict__ W1t,
    const float* __restrict__ b1, const int* __restrict__ token_list,
    const int* __restrict__ offsets, const int* __restrict__ tile_e,
    const int* __restrict__ tile_ms, const int* __restrict__ total_tiles,
    unsigned short* __restrict__ hbuf) {
  __shared__ __align__(16) unsigned short ldsA[128 * 32];
  __shared__ __align__(16) unsigned short ldsB[128 * 32];

  int bx = blockIdx.x;
  int t = (bx & 7) * 17 + (bx >> 3);  // XCD swizzle: each XCD gets contiguous m-chunk
  if (t >= *total_tiles) return;
  int e = tile_e[t], mstart = tile_ms[t];
  int base = offsets[e], endp = offsets[e + 1];
  int ntile = blockIdx.y;

  int tid = threadIdx.x;
  int lane = tid & 63, wid = tid >> 6;
  int wr = wid & 1, wc = wid >> 1;
  int quad = lane >> 4, l16 = lane & 15;

  int rowA = tid >> 2, slot = tid & 3;
  int sw = slot ^ (rowA & 3) ^ ((rowA >> 2) & 3);
  int p0 = base + mstart + rowA;
  int p1 = p0 + 64;
  int tok0 = token_list[p0 < endp ? p0 : endp - 1];
  int tok1 = token_list[p1 < endp ? p1 : endp - 1];
  int offA0 = tok0 * DDIM + sw * 8;
  int offA1 = tok1 * DDIM + sw * 8;
  int offB0 = e * (HDIM * DDIM) + (ntile * 128 + rowA) * DDIM + sw * 8;
  int offB1 = offB0 + 64 * DDIM;
  unsigned short* la0 = &ldsA[tid * 8];
  unsigned short* la1 = &ldsA[2048 + tid * 8];
  unsigned short* lb0 = &ldsB[tid * 8];
  unsigned short* lb1 = &ldsB[2048 + tid * 8];

  int swq = (quad ^ (l16 & 3) ^ ((l16 >> 2) & 3)) * 8;

  f32x4 acc[4][4];
#pragma unroll
  for (int i = 0; i < 4; ++i)
#pragma unroll
    for (int j = 0; j < 4; ++j) acc[i][j] = (f32x4)0.0f;

  for (int k0 = 0; k0 < DDIM; k0 += 32) {
    gload16(xbf + offA0 + k0, la0);
    gload16(xbf + offA1 + k0, la1);
    gload16(W1t + offB0 + k0, lb0);
    gload16(W1t + offB1 + k0, lb1);
    __syncthreads();
    short8 af[4], bfr[4];
#pragma unroll
    for (int i = 0; i < 4; ++i)
      af[i] = *(const short8*)(&ldsA[(wr * 64 + 16 * i + l16) * 32 + swq]);
#pragma unroll
    for (int j = 0; j < 4; ++j)
      bfr[j] = *(const short8*)(&ldsB[(wc * 64 + 16 * j + l16) * 32 + swq]);
#pragma unroll
    for (int i = 0; i < 4; ++i)
#pragma unroll
      for (int j = 0; j < 4; ++j)
        acc[i][j] = __builtin_amdgcn_mfma_f32_16x16x32_bf16(af[i], bfr[j], acc[i][j], 0, 0, 0);
    __syncthreads();
  }

  const float* b1e = b1 + (size_t)e * HDIM + ntile * 128;
#pragma unroll
  for (int i = 0; i < 4; ++i) {
#pragma unroll
    for (int r = 0; r < 4; ++r) {
      int row = wr * 64 + 16 * i + quad * 4 + r;
      int p = base + mstart + row;
      if (p < endp) {
        size_t ob = (size_t)p * HDIM + ntile * 128;
#pragma unroll
        for (int j = 0; j < 4; ++j) {
          int col = wc * 64 + 16 * j + l16;
          float v = acc[i][j][r] + b1e[col];
          hbuf[ob + col] = (unsigned short)bf16r(gelu_fast(v));
        }
      }
    }
  }
}

// ---------------- GEMM2: out[tok] = (h @ W2[e] + b2[e]) * top_score ----------------
// BM=192 (wave tile 96x64, 6x4 frags): grid = 96*8 = 768 = exactly 3 blocks/CU at
// launch_bounds(256,3) -> one scheduling round, no 53% tail quantization.
// Swizzle formulas survive BM=192 since 96 ≡ 0 (mod 4).
__global__ __launch_bounds__(256, 3) void gemm2_kernel(
    const unsigned short* __restrict__ hbuf, const unsigned short* __restrict__ W2t,
    const float* __restrict__ b2, const int* __restrict__ token_list,
    const int* __restrict__ offsets, const int* __restrict__ tile2_e,
    const int* __restrict__ tile2_ms, const int* __restrict__ total_tiles2,
    const float* __restrict__ tscore, float* __restrict__ out) {
  __shared__ __align__(16) unsigned short ldsA[192 * 32];
  __shared__ __align__(16) unsigned short ldsB[128 * 32];

  int bx = blockIdx.x;
  int t = (bx & 7) * 12 + (bx >> 3);  // XCD swizzle: 96 = 8*12
  if (t >= *total_tiles2) return;
  int e = tile2_e[t], mstart = tile2_ms[t];
  int base = offsets[e], endp = offsets[e + 1];
  int ntile = blockIdx.y;

  int tid = threadIdx.x;
  int lane = tid & 63, wid = tid >> 6;
  int wr = wid & 1, wc = wid >> 1;
  int quad = lane >> 4, l16 = lane & 15;

  int rowA = tid >> 2, slot = tid & 3;
  int sw = slot ^ (rowA & 3) ^ ((rowA >> 2) & 3);
  int p0 = base + mstart + rowA;
  int pe0 = p0 < endp ? p0 : endp - 1;
  int pe1 = p0 + 64 < endp ? p0 + 64 : endp - 1;
  int pe2 = p0 + 128 < endp ? p0 + 128 : endp - 1;
  int offA0 = pe0 * HDIM + sw * 8;
  int offA1 = pe1 * HDIM + sw * 8;
  int offA2 = pe2 * HDIM + sw * 8;
  int offB0 = e * (HDIM * DDIM) + (ntile * 128 + rowA) * HDIM + sw * 8;
  int offB1 = offB0 + 64 * HDIM;
  unsigned short* la0 = &ldsA[tid * 8];
  unsigned short* la1 = &ldsA[2048 + tid * 8];
  unsigned short* la2 = &ldsA[4096 + tid * 8];
  unsigned short* lb0 = &ldsB[tid * 8];
  unsigned short* lb1 = &ldsB[2048 + tid * 8];

  int swq = (quad ^ (l16 & 3) ^ ((l16 >> 2) & 3)) * 8;

  f32x4 acc[6][4];
#pragma unroll
  for (int i = 0; i < 6; ++i)
#pragma unroll
    for (int j = 0; j < 4; ++j) acc[i][j] = (f32x4)0.0f;

  for (int k0 = 0; k0 < HDIM; k0 += 32) {
    gload16(hbuf + offA0 + k0, la0);
    gload16(hbuf + offA1 + k0, la1);
    gload16(hbuf + offA2 + k0, la2);
    gload16(W2t + offB0 + k0, lb0);
    gload16(W2t + offB1 + k0, lb1);
    __syncthreads();
    short8 af[6], bfr[4];
#pragma unroll
    for (int i = 0; i < 6; ++i)
      af[i] = *(const short8*)(&ldsA[(wr * 96 + 16 * i + l16) * 32 + swq]);
#pragma unroll
    for (int j = 0; j < 4; ++j)
      bfr[j] = *(const short8*)(&ldsB[(wc * 64 + 16 * j + l16) * 32 + swq]);
#pragma unroll
    for (int i = 0; i < 6; ++i)
#pragma unroll
      for (int j = 0; j < 4; ++j)
        acc[i][j] = __builtin_amdgcn_mfma_f32_16x16x32_bf16(af[i], bfr[j], acc[i][j], 0, 0, 0);
    __syncthreads();
  }

  const float* b2e = b2 + (size_t)e * DDIM + ntile * 128;
#pragma unroll
  for (int i = 0; i < 6; ++i) {
#pragma unroll
    for (int r = 0; r < 4; ++r) {
      int row = wr * 96 + 16 * i + quad * 4 + r;
      int p = base + mstart + row;
      if (p < endp) {
        int tok = token_list[p];
        float ts = tscore[tok];
        size_t ob = (size_t)tok * DDIM + ntile * 128;
#pragma unroll
        for (int j = 0; j < 4; ++j) {
          int col = wc * 64 + 16 * j + l16;
          out[ob + col] = (acc[i][j][r] + b2e[col]) * ts;
        }
      }
    }
  }
}

extern "C" void kernel_launch(void* const* d_in, const int* in_sizes, int n_in,
                              void* d_out, int out_size, void* d_ws, size_t ws_size,
                              hipStream_t stream) {
  const float* x  = (const float*)d_in[0];
  const float* Wg = (const float*)d_in[1];
  const float* W1 = (const float*)d_in[2];
  const float* b1 = (const float*)d_in[3];
  const float* W2 = (const float*)d_in[4];
  const float* b2 = (const float*)d_in[5];

  float* out_main = (float*)d_out;
  float* gate_out = out_main + (size_t)BTOK * DDIM;
  float* texp_out = gate_out + (size_t)BTOK * NEXP;
  float* dens_out = texp_out + BTOK;

  char* w = (char*)d_ws;
  size_t off = 0;
  unsigned short* hbuf = (unsigned short*)(w + off); off += (size_t)BTOK * HDIM * 2;  // 134 MB
  unsigned short* xbf  = (unsigned short*)(w + off); off += (size_t)BTOK * DDIM * 2;  // 33.5 MB
  unsigned short* W1t  = (unsigned short*)(w + off); off += (size_t)NEXP * DDIM * HDIM * 2;  // 67 MB
  unsigned short* W2t  = (unsigned short*)(w + off); off += (size_t)NEXP * DDIM * HDIM * 2;  // 67 MB
  float* tscore     = (float*)(w + off); off += (size_t)BTOK * 4;
  int* expert_ws    = (int*)(w + off);   off += (size_t)BTOK * 4;
  int* token_list   = (int*)(w + off);   off += (size_t)BTOK * 4;
  int* counts       = (int*)(w + off);   off += 256;
  int* offsets      = (int*)(w + off);   off += 256;
  int* cursors      = (int*)(w + off);   off += 256;
  int* tile_e       = (int*)(w + off);   off += 1024;
  int* tile_ms      = (int*)(w + off);   off += 1024;
  int* total_tiles  = (int*)(w + off);   off += 256;
  int* tile2_e      = (int*)(w + off);   off += 512;
  int* tile2_ms     = (int*)(w + off);   off += 512;
  int* total_tiles2 = (int*)(w + off);   off += 256;

  hipLaunchKernelGGL(gate_kernel, dim3(BTOK / 4), dim3(256), 0, stream,
                     x, Wg, gate_out, texp_out, tscore, expert_ws, xbf);
  hipLaunchKernelGGL(plan_kernel, dim3(1), dim3(1024), 0, stream,
                     expert_ws, counts, offsets, cursors,
                     tile_e, tile_ms, total_tiles,
                     tile2_e, tile2_ms, total_tiles2, dens_out);
  hipLaunchKernelGGL(scatter_kernel, dim3(BTOK / 256), dim3(256), 0, stream,
                     expert_ws, cursors, token_list);
  hipLaunchKernelGGL(transpose_cvt_kernel, dim3(HDIM / 64, DDIM / 64, NEXP), dim3(256), 0, stream,
                     W1, W1t, DDIM, HDIM);
  hipLaunchKernelGGL(transpose_cvt_kernel, dim3(DDIM / 64, HDIM / 64, NEXP), dim3(256), 0, stream,
                     W2, W2t, HDIM, DDIM);
  hipLaunchKernelGGL(gemm1_kernel, dim3(MAXT, HDIM / 128), dim3(256), 0, stream,
                     xbf, W1t, b1, token_list, offsets, tile_e, tile_ms, total_tiles, hbuf);
  hipLaunchKernelGGL(gemm2_kernel, dim3(MAXT2, DDIM / 128), dim3(256), 0, stream,
                     hbuf, W2t, b2, token_list, offsets, tile2_e, tile2_ms, total_tiles2, tscore, out_main);
}

// Round 2
// 780.065 us; speedup vs baseline: 1.4360x; 1.0143x over previous
//
#include <hip/hip_runtime.h>
#include <math.h>

#define BTOK 16384
#define DDIM 1024
#define HDIM 4096
#define NEXP 8
#define MAXT1 72    // gemm1 m-tiles (BM=256): <= 64 + 8 partials
#define MAXT2 96    // gemm2 m-tiles (BM=192): <= 93, padded to mult of 8

typedef float f32x4 __attribute__((ext_vector_type(4)));
typedef short short8 __attribute__((ext_vector_type(8)));

__device__ __forceinline__ unsigned int bf16r(float f) {
  unsigned int u = __float_as_uint(f);
  return (u + 0x7fffu + ((u >> 16) & 1u)) >> 16;  // RTN-even
}
__device__ __forceinline__ unsigned int pack2(float a, float b) {
  return bf16r(a) | (bf16r(b) << 16);
}
// tanh-GELU via exp: x*(1 - 1/(1+e^{2t})), t = sqrt(2/pi)(x+0.044715x^3)
__device__ __forceinline__ float gelu_fast(float x) {
  float t = 0.7978845608028654f * x * (1.0f + 0.044715f * x * x);
  float e = __expf(2.0f * t);
  return x * (1.0f - __builtin_amdgcn_rcpf(e + 1.0f));
}
// async global->LDS, 16B per lane; LDS dest must be uniform base + lane*16
__device__ __forceinline__ void gload16(const void* g, void* l) {
  __builtin_amdgcn_global_load_lds(
      (const __attribute__((address_space(1))) unsigned int*)g,
      (__attribute__((address_space(3))) unsigned int*)l, 16, 0, 0);
}

// ---------------- gating: fp64 logits, softmax, argmax; also emits x in bf16 ----------------
__global__ __launch_bounds__(256) void gate_kernel(
    const float* __restrict__ x, const float* __restrict__ Wg,
    float* __restrict__ gate_out, float* __restrict__ texp_out,
    float* __restrict__ tscore, int* __restrict__ expert_ws,
    unsigned short* __restrict__ xbf) {
  int wid = threadIdx.x >> 6, lane = threadIdx.x & 63;
  int b = blockIdx.x * 4 + wid;
  const float* xr = x + (size_t)b * DDIM;
  unsigned short* xbr = xbf + (size_t)b * DDIM;
  double acc[8];
#pragma unroll
  for (int e = 0; e < 8; ++e) acc[e] = 0.0;
#pragma unroll
  for (int i = 0; i < 4; ++i) {
    int d0 = (i * 64 + lane) * 4;
    float4 v = *(const float4*)(xr + d0);
    uint2 o;
    o.x = pack2(v.x, v.y);
    o.y = pack2(v.z, v.w);
    *(uint2*)(xbr + d0) = o;  // fused x -> bf16 conversion
    const float4* wp = (const float4*)(Wg + (size_t)d0 * 8);
    float xs[4] = {v.x, v.y, v.z, v.w};
#pragma unroll
    for (int j = 0; j < 4; ++j) {
      float4 w0 = wp[2 * j], w1 = wp[2 * j + 1];
      double xv = (double)xs[j];
      acc[0] += xv * (double)w0.x;
      acc[1] += xv * (double)w0.y;
      acc[2] += xv * (double)w0.z;
      acc[3] += xv * (double)w0.w;
      acc[4] += xv * (double)w1.x;
      acc[5] += xv * (double)w1.y;
      acc[6] += xv * (double)w1.z;
      acc[7] += xv * (double)w1.w;
    }
  }
#pragma unroll
  for (int off = 32; off > 0; off >>= 1) {
#pragma unroll
    for (int e = 0; e < 8; ++e) acc[e] += __shfl_down(acc[e], off, 64);
  }
  if (lane == 0) {
    double mx = acc[0];
#pragma unroll
    for (int e = 1; e < 8; ++e) mx = acc[e] > mx ? acc[e] : mx;
    double ex[8], s = 0.0;
#pragma unroll
    for (int e = 0; e < 8; ++e) { ex[e] = exp(acc[e] - mx); s += ex[e]; }
    int best = 0;
#pragma unroll
    for (int e = 1; e < 8; ++e) if (acc[e] > acc[best]) best = e;  // first-max
    double inv = 1.0 / s;
#pragma unroll
    for (int e = 0; e < 8; ++e) gate_out[(size_t)b * 8 + e] = (float)(ex[e] * inv);
    texp_out[b] = (float)best;
    tscore[b] = (float)(ex[best] * inv);
    expert_ws[b] = best;
  }
}

// ---------------- plan: ballot histogram + offsets + tile worklists (1 block) ----------------
__global__ __launch_bounds__(1024) void plan_kernel(
    const int* __restrict__ expert_ws, int* __restrict__ counts,
    int* __restrict__ offsets, int* __restrict__ cursors,
    int* __restrict__ tile1_e, int* __restrict__ tile1_ms, int* __restrict__ total_tiles1,
    int* __restrict__ tile2_e, int* __restrict__ tile2_ms, int* __restrict__ total_tiles2,
    float* __restrict__ dens_out) {
  __shared__ int wcnt[16][8];
  __shared__ int tot[8];
  int tid = threadIdx.x, lane = tid & 63, wid = tid >> 6;
  int cnt[8];
#pragma unroll
  for (int e = 0; e < 8; ++e) cnt[e] = 0;
  for (int i = 0; i < 16; ++i) {
    int e = expert_ws[wid * 1024 + i * 64 + lane];
#pragma unroll
    for (int ee = 0; ee < 8; ++ee) {
      unsigned long long m = __ballot(e == ee);
      cnt[ee] += __popcll(m);
    }
  }
  if (lane == 0) {
#pragma unroll
    for (int e = 0; e < 8; ++e) wcnt[wid][e] = cnt[e];
  }
  __syncthreads();
  if (tid < 8) {
    int s = 0;
    for (int w = 0; w < 16; ++w) s += wcnt[w][tid];
    tot[tid] = s;
    counts[tid] = s;
  }
  __syncthreads();
  if (tid == 0) {
    int off = 0, t1 = 0, t2 = 0;
    for (int e = 0; e < NEXP; ++e) {
      int c = tot[e];
      offsets[e] = off;
      cursors[e] = off;
      dens_out[e] = (float)c / (float)BTOK;
      for (int ms = 0; ms < c; ms += 256) { tile1_e[t1] = e; tile1_ms[t1] = ms; ++t1; }
      for (int ms = 0; ms < c; ms += 192) { tile2_e[t2] = e; tile2_ms[t2] = ms; ++t2; }
      off += c;
    }
    offsets[NEXP] = off;
    *total_tiles1 = t1;
    *total_tiles2 = t2;
  }
}

// ---------------- scatter: block-aggregated ranks, 8 atomics per block ----------------
__global__ __launch_bounds__(256) void scatter_kernel(
    const int* __restrict__ expert_ws, int* __restrict__ cursors,
    int* __restrict__ token_list) {
  __shared__ int wbase[4][8];
  __shared__ int bbase[8];
  int tid = threadIdx.x, lane = tid & 63, wid = tid >> 6;
  int b = blockIdx.x * 256 + tid;
  int e = expert_ws[b];
  unsigned long long mymask = 0;
  int wc[8];
#pragma unroll
  for (int ee = 0; ee < 8; ++ee) {
    unsigned long long m = __ballot(e == ee);
    wc[ee] = __popcll(m);
    if (ee == e) mymask = m;
  }
  int rank = __popcll(mymask & ((1ull << lane) - 1ull));
  if (lane == 0) {
#pragma unroll
    for (int ee = 0; ee < 8; ++ee) wbase[wid][ee] = wc[ee];
  }
  __syncthreads();
  if (tid < 8) {
    int s0 = wbase[0][tid], s1 = wbase[1][tid], s2 = wbase[2][tid], s3 = wbase[3][tid];
    int t = s0 + s1 + s2 + s3;
    bbase[tid] = atomicAdd(&cursors[tid], t);
    wbase[0][tid] = 0;
    wbase[1][tid] = s0;
    wbase[2][tid] = s0 + s1;
    wbase[3][tid] = s0 + s1 + s2;
  }
  __syncthreads();
  token_list[bbase[e] + wbase[wid][e] + rank] = b;
}

// ---------------- transpose + convert: in[z][R][C] fp32 -> out[z][C][R] bf16 ----------------
__global__ __launch_bounds__(256) void transpose_cvt_kernel(
    const float* __restrict__ in, unsigned short* __restrict__ out, int R, int C) {
  __shared__ unsigned short tT[64 * 68];  // [col][row^swz], pad 68
  const float* ine = in + (size_t)blockIdx.z * R * C;
  unsigned short* oute = out + (size_t)blockIdx.z * R * C;
  int r0 = blockIdx.y * 64, c0 = blockIdx.x * 64;
  int tid = threadIdx.x;
#pragma unroll
  for (int l = 0; l < 4; ++l) {
    int f = tid + 256 * l;           // 0..1023
    int r = f >> 4, c4 = f & 15;     // row, float4-col
    float4 v = *(const float4*)(ine + (size_t)(r0 + r) * C + c0 + c4 * 4);
#pragma unroll
    for (int i = 0; i < 4; ++i) {
      int cc = 4 * c4 + i;
      int s = ((cc >> 4) & 3) << 2;
      float val = i == 0 ? v.x : (i == 1 ? v.y : (i == 2 ? v.z : v.w));
      tT[cc * 68 + (r ^ s)] = (unsigned short)bf16r(val);
    }
  }
  __syncthreads();
#pragma unroll
  for (int l = 0; l < 4; ++l) {
    int f = tid + 256 * l;           // 0..1023
    int oc = f >> 4, h4 = f & 15;    // out-row (=col), 4-row chunk
    int s = ((oc >> 4) & 3) << 2;
    uint2 o = *(const uint2*)(&tT[oc * 68 + ((4 * h4) ^ s)]);  // rows 4h4..4h4+3
    *(uint2*)(oute + (size_t)(c0 + oc) * R + r0 + 4 * h4) = o;
  }
}

// ---------------- GEMM1: 256x256 tile, BK=64, dbuf LDS + counted vmcnt (T3+T4),
// 4 MFMA phases/K-tile with frag reuse, XOR swizzle slot=q^(r&7) (T2), setprio (T5).
// 512 thr = 8 waves (2x4), wave tile 128x64 = acc[8][4]. LDS 128 KB.
__global__ __launch_bounds__(512, 1) void gemm1_kernel(
    const unsigned short* __restrict__ xbf, const unsigned short* __restrict__ W1t,
    const float* __restrict__ b1, const int* __restrict__ token_list,
    const int* __restrict__ offsets, const int* __restrict__ tile1_e,
    const int* __restrict__ tile1_ms, const int* __restrict__ total_tiles1,
    unsigned short* __restrict__ hbuf) {
  __shared__ __align__(16) unsigned short lds[65536];  // 2 buf x (A 16384 + B 16384 shorts)

  int bx = blockIdx.x;
  int t = (bx & 7) * 9 + (bx >> 3);  // XCD swizzle, 72 = 8*9 (bijective)
  if (t >= *total_tiles1) return;
  int e = tile1_e[t], mstart = tile1_ms[t];
  int base = offsets[e], endp = offsets[e + 1];
  int ntile = blockIdx.y;

  int tid = threadIdx.x;
  int lane = tid & 63, wid = tid >> 6;
  int wm = wid & 1, wn = wid >> 1;      // 2 x 4 waves
  int quad = lane >> 4, l16 = lane & 15;

  // ---- staging addresses: thread stages chunk (tid&7)^((tid>>3)&7) of rows 64j+(tid>>3)
  int g = (tid & 7) ^ ((tid >> 3) & 7);
  int aoff[4], boff[4];
#pragma unroll
  for (int j = 0; j < 4; ++j) {
    int r = 64 * j + (tid >> 3);
    int p = base + mstart + r;
    p = p < endp ? p : endp - 1;
    aoff[j] = token_list[p] * DDIM + g * 8;
    boff[j] = e * (HDIM * DDIM) + (ntile * 256 + r) * DDIM + g * 8;
  }

  int swq0 = (quad ^ (l16 & 7)) * 8;        // k-chunk 0..3 (kk=0)
  int swq1 = ((4 + quad) ^ (l16 & 7)) * 8;  // k-chunk 4..7 (kk=1)

  f32x4 acc[8][4];
#pragma unroll
  for (int i = 0; i < 8; ++i)
#pragma unroll
    for (int j = 0; j < 4; ++j) acc[i][j] = (f32x4)0.0f;

  // prologue: stage K-tile 0 into buf0
  {
    unsigned short* LA = lds + tid * 8;
#pragma unroll
    for (int j = 0; j < 4; ++j) gload16(xbf + aoff[j], LA + j * 4096);
#pragma unroll
    for (int j = 0; j < 4; ++j) gload16(W1t + boff[j], LA + 16384 + j * 4096);
  }

  const int NT = DDIM / 64;  // 16
  for (int kt = 0; kt < NT; ++kt) {
    int cb = (kt & 1) * 32768;
    if (kt + 1 < NT) {
      // prefetch next K-tile into other buffer; wait only for CURRENT tile's 8 loads
      int nb = ((kt + 1) & 1) * 32768;
      unsigned short* LA = lds + nb + tid * 8;
      int ko = (kt + 1) * 64;
#pragma unroll
      for (int j = 0; j < 4; ++j) gload16(xbf + aoff[j] + ko, LA + j * 4096);
#pragma unroll
      for (int j = 0; j < 4; ++j) gload16(W1t + boff[j] + ko, LA + 16384 + j * 4096);
      asm volatile("s_waitcnt vmcnt(8)");
    } else {
      asm volatile("s_waitcnt vmcnt(0)");
    }
    __builtin_amdgcn_sched_barrier(0);
    __builtin_amdgcn_s_barrier();
    __builtin_amdgcn_sched_barrier(0);

    const unsigned short* Ab = lds + cb + (wm * 128 + l16) * 64;
    const unsigned short* Bb = lds + cb + 16384 + (wn * 64 + l16) * 64;
    short8 a[4][2], b0[2][2], b1v[2][2];
    // phase 0: A-half0 + B-lo -> acc[0..3][0..1]
#pragma unroll
    for (int fi = 0; fi < 4; ++fi) {
      a[fi][0] = *(const short8*)(Ab + fi * 1024 + swq0);
      a[fi][1] = *(const short8*)(Ab + fi * 1024 + swq1);
    }
#pragma unroll
    for (int fj = 0; fj < 2; ++fj) {
      b0[fj][0] = *(const short8*)(Bb + fj * 1024 + swq0);
      b0[fj][1] = *(const short8*)(Bb + fj * 1024 + swq1);
    }
    __builtin_amdgcn_s_setprio(1);
#pragma unroll
    for (int fi = 0; fi < 4; ++fi)
#pragma unroll
      for (int fj = 0; fj < 2; ++fj) {
        acc[fi][fj] = __builtin_amdgcn_mfma_f32_16x16x32_bf16(a[fi][0], b0[fj][0], acc[fi][fj], 0, 0, 0);
        acc[fi][fj] = __builtin_amdgcn_mfma_f32_16x16x32_bf16(a[fi][1], b0[fj][1], acc[fi][fj], 0, 0, 0);
      }
    __builtin_amdgcn_s_setprio(0);
    // phase 1: B-hi -> acc[0..3][2..3] (A-half0 reused)
#pragma unroll
    for (int fj = 0; fj < 2; ++fj) {
      b1v[fj][0] = *(const short8*)(Bb + (2 + fj) * 1024 + swq0);
      b1v[fj][1] = *(const short8*)(Bb + (2 + fj) * 1024 + swq1);
    }
    __builtin_amdgcn_s_setprio(1);
#pragma unroll
    for (int fi = 0; fi < 4; ++fi)
#pragma unroll
      for (int fj = 0; fj < 2; ++fj) {
        acc[fi][2 + fj] = __builtin_amdgcn_mfma_f32_16x16x32_bf16(a[fi][0], b1v[fj][0], acc[fi][2 + fj], 0, 0, 0);
        acc[fi][2 + fj] = __builtin_amdgcn_mfma_f32_16x16x32_bf16(a[fi][1], b1v[fj][1], acc[fi][2 + fj], 0, 0, 0);
      }
    __builtin_amdgcn_s_setprio(0);
    // phase 2: A-half1 -> acc[4..7][2..3] (B-hi reused)
#pragma unroll
    for (int fi = 0; fi < 4; ++fi) {
      a[fi][0] = *(const short8*)(Ab + 4096 + fi * 1024 + swq0);
      a[fi][1] = *(const short8*)(Ab + 4096 + fi * 1024 + swq1);
    }
    __builtin_amdgcn_s_setprio(1);
#pragma unroll
    for (int fi = 0; fi < 4; ++fi)
#pragma unroll
      for (int fj = 0; fj < 2; ++fj) {
        acc[4 + fi][2 + fj] = __builtin_amdgcn_mfma_f32_16x16x32_bf16(a[fi][0], b1v[fj][0], acc[4 + fi][2 + fj], 0, 0, 0);
        acc[4 + fi][2 + fj] = __builtin_amdgcn_mfma_f32_16x16x32_bf16(a[fi][1], b1v[fj][1], acc[4 + fi][2 + fj], 0, 0, 0);
      }
    __builtin_amdgcn_s_setprio(0);
    // phase 3: A-half1 x B-lo -> acc[4..7][0..1] (no new reads)
    __builtin_amdgcn_s_setprio(1);
#pragma unroll
    for (int fi = 0; fi < 4; ++fi)
#pragma unroll
      for (int fj = 0; fj < 2; ++fj) {
        acc[4 + fi][fj] = __builtin_amdgcn_mfma_f32_16x16x32_bf16(a[fi][0], b0[fj][0], acc[4 + fi][fj], 0, 0, 0);
        acc[4 + fi][fj] = __builtin_amdgcn_mfma_f32_16x16x32_bf16(a[fi][1], b0[fj][1], acc[4 + fi][fj], 0, 0, 0);
      }
    __builtin_amdgcn_s_setprio(0);

    __builtin_amdgcn_sched_barrier(0);
    __builtin_amdgcn_s_barrier();  // protect buf[cb] before next iter restages it
    __builtin_amdgcn_sched_barrier(0);
  }

  const float* b1e = b1 + (size_t)e * HDIM + ntile * 256;
#pragma unroll
  for (int hm = 0; hm < 2; ++hm) {
#pragma unroll
    for (int fi = 0; fi < 4; ++fi) {
#pragma unroll
      for (int rg = 0; rg < 4; ++rg) {
        int row = wm * 128 + hm * 64 + fi * 16 + quad * 4 + rg;
        int p = base + mstart + row;
        if (p < endp) {
          size_t ob = (size_t)p * HDIM + ntile * 256;
#pragma unroll
          for (int fj = 0; fj < 4; ++fj) {
            int col = wn * 64 + fj * 16 + l16;
            float v = acc[hm * 4 + fi][fj][rg] + b1e[col];
            hbuf[ob + col] = (unsigned short)bf16r(gelu_fast(v));
          }
        }
      }
    }
  }
}

// ---------------- GEMM2: out[tok] = (h @ W2[e] + b2[e]) * top_score ----------------
// BM=192 (wave tile 96x64, 6x4 frags): grid = 96*8 = 768 = exactly 3 blocks/CU.
__global__ __launch_bounds__(256, 3) void gemm2_kernel(
    const unsigned short* __restrict__ hbuf, const unsigned short* __restrict__ W2t,
    const float* __restrict__ b2, const int* __restrict__ token_list,
    const int* __restrict__ offsets, const int* __restrict__ tile2_e,
    const int* __restrict__ tile2_ms, const int* __restrict__ total_tiles2,
    const float* __restrict__ tscore, float* __restrict__ out) {
  __shared__ __align__(16) unsigned short ldsA[192 * 32];
  __shared__ __align__(16) unsigned short ldsB[128 * 32];

  int bx = blockIdx.x;
  int t = (bx & 7) * 12 + (bx >> 3);  // XCD swizzle: 96 = 8*12
  if (t >= *total_tiles2) return;
  int e = tile2_e[t], mstart = tile2_ms[t];
  int base = offsets[e], endp = offsets[e + 1];
  int ntile = blockIdx.y;

  int tid = threadIdx.x;
  int lane = tid & 63, wid = tid >> 6;
  int wr = wid & 1, wc = wid >> 1;
  int quad = lane >> 4, l16 = lane & 15;

  int rowA = tid >> 2, slot = tid & 3;
  int sw = slot ^ (rowA & 3) ^ ((rowA >> 2) & 3);
  int p0 = base + mstart + rowA;
  int pe0 = p0 < endp ? p0 : endp - 1;
  int pe1 = p0 + 64 < endp ? p0 + 64 : endp - 1;
  int pe2 = p0 + 128 < endp ? p0 + 128 : endp - 1;
  int offA0 = pe0 * HDIM + sw * 8;
  int offA1 = pe1 * HDIM + sw * 8;
  int offA2 = pe2 * HDIM + sw * 8;
  int offB0 = e * (HDIM * DDIM) + (ntile * 128 + rowA) * HDIM + sw * 8;
  int offB1 = offB0 + 64 * HDIM;
  unsigned short* la0 = &ldsA[tid * 8];
  unsigned short* la1 = &ldsA[2048 + tid * 8];
  unsigned short* la2 = &ldsA[4096 + tid * 8];
  unsigned short* lb0 = &ldsB[tid * 8];
  unsigned short* lb1 = &ldsB[2048 + tid * 8];

  int swq = (quad ^ (l16 & 3) ^ ((l16 >> 2) & 3)) * 8;

  f32x4 acc[6][4];
#pragma unroll
  for (int i = 0; i < 6; ++i)
#pragma unroll
    for (int j = 0; j < 4; ++j) acc[i][j] = (f32x4)0.0f;

  for (int k0 = 0; k0 < HDIM; k0 += 32) {
    gload16(hbuf + offA0 + k0, la0);
    gload16(hbuf + offA1 + k0, la1);
    gload16(hbuf + offA2 + k0, la2);
    gload16(W2t + offB0 + k0, lb0);
    gload16(W2t + offB1 + k0, lb1);
    __syncthreads();
    short8 af[6], bfr[4];
#pragma unroll
    for (int i = 0; i < 6; ++i)
      af[i] = *(const short8*)(&ldsA[(wr * 96 + 16 * i + l16) * 32 + swq]);
#pragma unroll
    for (int j = 0; j < 4; ++j)
      bfr[j] = *(const short8*)(&ldsB[(wc * 64 + 16 * j + l16) * 32 + swq]);
#pragma unroll
    for (int i = 0; i < 6; ++i)
#pragma unroll
      for (int j = 0; j < 4; ++j)
        acc[i][j] = __builtin_amdgcn_mfma_f32_16x16x32_bf16(af[i], bfr[j], acc[i][j], 0, 0, 0);
    __syncthreads();
  }

  const float* b2e = b2 + (size_t)e * DDIM + ntile * 128;
#pragma unroll
  for (int i = 0; i < 6; ++i) {
#pragma unroll
    for (int r = 0; r < 4; ++r) {
      int row = wr * 96 + 16 * i + quad * 4 + r;
      int p = base + mstart + row;
      if (p < endp) {
        int tok = token_list[p];
        float ts = tscore[tok];
        size_t ob = (size_t)tok * DDIM + ntile * 128;
#pragma unroll
        for (int j = 0; j < 4; ++j) {
          int col = wc * 64 + 16 * j + l16;
          out[ob + col] = (acc[i][j][r] + b2e[col]) * ts;
        }
      }
    }
  }
}

extern "C" void kernel_launch(void* const* d_in, const int* in_sizes, int n_in,
                              void* d_out, int out_size, void* d_ws, size_t ws_size,
                              hipStream_t stream) {
  const float* x  = (const float*)d_in[0];
  const float* Wg = (const float*)d_in[1];
  const float* W1 = (const float*)d_in[2];
  const float* b1 = (const float*)d_in[3];
  const float* W2 = (const float*)d_in[4];
  const float* b2 = (const float*)d_in[5];

  float* out_main = (float*)d_out;
  float* gate_out = out_main + (size_t)BTOK * DDIM;
  float* texp_out = gate_out + (size_t)BTOK * NEXP;
  float* dens_out = texp_out + BTOK;

  char* w = (char*)d_ws;
  size_t off = 0;
  unsigned short* hbuf = (unsigned short*)(w + off); off += (size_t)BTOK * HDIM * 2;  // 134 MB
  unsigned short* xbf  = (unsigned short*)(w + off); off += (size_t)BTOK * DDIM * 2;  // 33.5 MB
  unsigned short* W1t  = (unsigned short*)(w + off); off += (size_t)NEXP * DDIM * HDIM * 2;  // 67 MB
  unsigned short* W2t  = (unsigned short*)(w + off); off += (size_t)NEXP * DDIM * HDIM * 2;  // 67 MB
  float* tscore     = (float*)(w + off); off += (size_t)BTOK * 4;
  int* expert_ws    = (int*)(w + off);   off += (size_t)BTOK * 4;
  int* token_list   = (int*)(w + off);   off += (size_t)BTOK * 4;
  int* counts       = (int*)(w + off);   off += 256;
  int* offsets      = (int*)(w + off);   off += 256;
  int* cursors      = (int*)(w + off);   off += 256;
  int* tile1_e      = (int*)(w + off);   off += 512;
  int* tile1_ms     = (int*)(w + off);   off += 512;
  int* total_tiles1 = (int*)(w + off);   off += 256;
  int* tile2_e      = (int*)(w + off);   off += 512;
  int* tile2_ms     = (int*)(w + off);   off += 512;
  int* total_tiles2 = (int*)(w + off);   off += 256;

  hipLaunchKernelGGL(gate_kernel, dim3(BTOK / 4), dim3(256), 0, stream,
                     x, Wg, gate_out, texp_out, tscore, expert_ws, xbf);
  hipLaunchKernelGGL(plan_kernel, dim3(1), dim3(1024), 0, stream,
                     expert_ws, counts, offsets, cursors,
                     tile1_e, tile1_ms, total_tiles1,
                     tile2_e, tile2_ms, total_tiles2, dens_out);
  hipLaunchKernelGGL(scatter_kernel, dim3(BTOK / 256), dim3(256), 0, stream,
                     expert_ws, cursors, token_list);
  hipLaunchKernelGGL(transpose_cvt_kernel, dim3(HDIM / 64, DDIM / 64, NEXP), dim3(256), 0, stream,
                     W1, W1t, DDIM, HDIM);
  hipLaunchKernelGGL(transpose_cvt_kernel, dim3(DDIM / 64, HDIM / 64, NEXP), dim3(256), 0, stream,
                     W2, W2t, HDIM, DDIM);
  hipLaunchKernelGGL(gemm1_kernel, dim3(MAXT1, HDIM / 256), dim3(512), 0, stream,
                     xbf, W1t, b1, token_list, offsets, tile1_e, tile1_ms, total_tiles1, hbuf);
  hipLaunchKernelGGL(gemm2_kernel, dim3(MAXT2, DDIM / 128), dim3(256), 0, stream,
                     hbuf, W2t, b2, token_list, offsets, tile2_e, tile2_ms, total_tiles2, tscore, out_main);
}

// Round 4
// 772.100 us; speedup vs baseline: 1.4509x; 1.0103x over previous
//
#include <hip/hip_runtime.h>
#include <math.h>

#define BTOK 16384
#define DDIM 1024
#define HDIM 4096
#define NEXP 8
#define MAXT1 72    // gemm1 m-tiles (BM=256): <= 64 + 8 partials
#define MAXT2 96    // gemm2 m-tiles (BM=192): <= 93, padded to mult of 8

typedef float f32x4 __attribute__((ext_vector_type(4)));
typedef short short8 __attribute__((ext_vector_type(8)));

__device__ __forceinline__ unsigned int bf16r(float f) {
  unsigned int u = __float_as_uint(f);
  return (u + 0x7fffu + ((u >> 16) & 1u)) >> 16;  // RTN-even
}
__device__ __forceinline__ unsigned int pack2(float a, float b) {
  return bf16r(a) | (bf16r(b) << 16);
}
// tanh-GELU via exp: x*(1 - 1/(1+e^{2t})), t = sqrt(2/pi)(x+0.044715x^3)
__device__ __forceinline__ float gelu_fast(float x) {
  float t = 0.7978845608028654f * x * (1.0f + 0.044715f * x * x);
  float e = __expf(2.0f * t);
  return x * (1.0f - __builtin_amdgcn_rcpf(e + 1.0f));
}
// async global->LDS, 16B per lane; LDS dest must be uniform base + lane*16
__device__ __forceinline__ void gload16(const void* g, void* l) {
  __builtin_amdgcn_global_load_lds(
      (const __attribute__((address_space(1))) unsigned int*)g,
      (__attribute__((address_space(3))) unsigned int*)l, 16, 0, 0);
}

#define MFMA16(a, b, c) __builtin_amdgcn_mfma_f32_16x16x32_bf16((a), (b), (c), 0, 0, 0)

// ---------------- gating: fp64 logits, softmax, argmax; also emits x in bf16 ----------------
__global__ __launch_bounds__(256) void gate_kernel(
    const float* __restrict__ x, const float* __restrict__ Wg,
    float* __restrict__ gate_out, float* __restrict__ texp_out,
    float* __restrict__ tscore, int* __restrict__ expert_ws,
    unsigned short* __restrict__ xbf) {
  int wid = threadIdx.x >> 6, lane = threadIdx.x & 63;
  int b = blockIdx.x * 4 + wid;
  const float* xr = x + (size_t)b * DDIM;
  unsigned short* xbr = xbf + (size_t)b * DDIM;
  double acc[8];
#pragma unroll
  for (int e = 0; e < 8; ++e) acc[e] = 0.0;
#pragma unroll
  for (int i = 0; i < 4; ++i) {
    int d0 = (i * 64 + lane) * 4;
    float4 v = *(const float4*)(xr + d0);
    uint2 o;
    o.x = pack2(v.x, v.y);
    o.y = pack2(v.z, v.w);
    *(uint2*)(xbr + d0) = o;  // fused x -> bf16 conversion
    const float4* wp = (const float4*)(Wg + (size_t)d0 * 8);
    float xs[4] = {v.x, v.y, v.z, v.w};
#pragma unroll
    for (int j = 0; j < 4; ++j) {
      float4 w0 = wp[2 * j], w1 = wp[2 * j + 1];
      double xv = (double)xs[j];
      acc[0] += xv * (double)w0.x;
      acc[1] += xv * (double)w0.y;
      acc[2] += xv * (double)w0.z;
      acc[3] += xv * (double)w0.w;
      acc[4] += xv * (double)w1.x;
      acc[5] += xv * (double)w1.y;
      acc[6] += xv * (double)w1.z;
      acc[7] += xv * (double)w1.w;
    }
  }
#pragma unroll
  for (int off = 32; off > 0; off >>= 1) {
#pragma unroll
    for (int e = 0; e < 8; ++e) acc[e] += __shfl_down(acc[e], off, 64);
  }
  if (lane == 0) {
    double mx = acc[0];
#pragma unroll
    for (int e = 1; e < 8; ++e) mx = acc[e] > mx ? acc[e] : mx;
    double ex[8], s = 0.0;
#pragma unroll
    for (int e = 0; e < 8; ++e) { ex[e] = exp(acc[e] - mx); s += ex[e]; }
    int best = 0;
#pragma unroll
    for (int e = 1; e < 8; ++e) if (acc[e] > acc[best]) best = e;  // first-max
    double inv = 1.0 / s;
#pragma unroll
    for (int e = 0; e < 8; ++e) gate_out[(size_t)b * 8 + e] = (float)(ex[e] * inv);
    texp_out[b] = (float)best;
    tscore[b] = (float)(ex[best] * inv);
    expert_ws[b] = best;
  }
}

// ---------------- plan: ballot histogram + offsets + tile worklists (1 block) ----------------
__global__ __launch_bounds__(1024) void plan_kernel(
    const int* __restrict__ expert_ws, int* __restrict__ counts,
    int* __restrict__ offsets, int* __restrict__ cursors,
    int* __restrict__ tile1_e, int* __restrict__ tile1_ms, int* __restrict__ total_tiles1,
    int* __restrict__ tile2_e, int* __restrict__ tile2_ms, int* __restrict__ total_tiles2,
    float* __restrict__ dens_out) {
  __shared__ int wcnt[16][8];
  __shared__ int tot[8];
  int tid = threadIdx.x, lane = tid & 63, wid = tid >> 6;
  int cnt[8];
#pragma unroll
  for (int e = 0; e < 8; ++e) cnt[e] = 0;
  for (int i = 0; i < 16; ++i) {
    int e = expert_ws[wid * 1024 + i * 64 + lane];
#pragma unroll
    for (int ee = 0; ee < 8; ++ee) {
      unsigned long long m = __ballot(e == ee);
      cnt[ee] += __popcll(m);
    }
  }
  if (lane == 0) {
#pragma unroll
    for (int e = 0; e < 8; ++e) wcnt[wid][e] = cnt[e];
  }
  __syncthreads();
  if (tid < 8) {
    int s = 0;
    for (int w = 0; w < 16; ++w) s += wcnt[w][tid];
    tot[tid] = s;
    counts[tid] = s;
  }
  __syncthreads();
  if (tid == 0) {
    int off = 0, t1 = 0, t2 = 0;
    for (int e = 0; e < NEXP; ++e) {
      int c = tot[e];
      offsets[e] = off;
      cursors[e] = off;
      dens_out[e] = (float)c / (float)BTOK;
      for (int ms = 0; ms < c; ms += 256) { tile1_e[t1] = e; tile1_ms[t1] = ms; ++t1; }
      for (int ms = 0; ms < c; ms += 192) { tile2_e[t2] = e; tile2_ms[t2] = ms; ++t2; }
      off += c;
    }
    offsets[NEXP] = off;
    *total_tiles1 = t1;
    *total_tiles2 = t2;
  }
}

// ---------------- scatter: block-aggregated ranks, 8 atomics per block ----------------
__global__ __launch_bounds__(256) void scatter_kernel(
    const int* __restrict__ expert_ws, int* __restrict__ cursors,
    int* __restrict__ token_list) {
  __shared__ int wbase[4][8];
  __shared__ int bbase[8];
  int tid = threadIdx.x, lane = tid & 63, wid = tid >> 6;
  int b = blockIdx.x * 256 + tid;
  int e = expert_ws[b];
  unsigned long long mymask = 0;
  int wc[8];
#pragma unroll
  for (int ee = 0; ee < 8; ++ee) {
    unsigned long long m = __ballot(e == ee);
    wc[ee] = __popcll(m);
    if (ee == e) mymask = m;
  }
  int rank = __popcll(mymask & ((1ull << lane) - 1ull));
  if (lane == 0) {
#pragma unroll
    for (int ee = 0; ee < 8; ++ee) wbase[wid][ee] = wc[ee];
  }
  __syncthreads();
  if (tid < 8) {
    int s0 = wbase[0][tid], s1 = wbase[1][tid], s2 = wbase[2][tid], s3 = wbase[3][tid];
    int t = s0 + s1 + s2 + s3;
    bbase[tid] = atomicAdd(&cursors[tid], t);
    wbase[0][tid] = 0;
    wbase[1][tid] = s0;
    wbase[2][tid] = s0 + s1;
    wbase[3][tid] = s0 + s1 + s2;
  }
  __syncthreads();
  token_list[bbase[e] + wbase[wid][e] + rank] = b;
}

// ---------------- transpose + convert: in[z][R][C] fp32 -> out[z][C][R] bf16 ----------------
__global__ __launch_bounds__(256) void transpose_cvt_kernel(
    const float* __restrict__ in, unsigned short* __restrict__ out, int R, int C) {
  __shared__ unsigned short tT[64 * 68];  // [col][row^swz], pad 68
  const float* ine = in + (size_t)blockIdx.z * R * C;
  unsigned short* oute = out + (size_t)blockIdx.z * R * C;
  int r0 = blockIdx.y * 64, c0 = blockIdx.x * 64;
  int tid = threadIdx.x;
#pragma unroll
  for (int l = 0; l < 4; ++l) {
    int f = tid + 256 * l;           // 0..1023
    int r = f >> 4, c4 = f & 15;     // row, float4-col
    float4 v = *(const float4*)(ine + (size_t)(r0 + r) * C + c0 + c4 * 4);
#pragma unroll
    for (int i = 0; i < 4; ++i) {
      int cc = 4 * c4 + i;
      int s = ((cc >> 4) & 3) << 2;
      float val = i == 0 ? v.x : (i == 1 ? v.y : (i == 2 ? v.z : v.w));
      tT[cc * 68 + (r ^ s)] = (unsigned short)bf16r(val);
    }
  }
  __syncthreads();
#pragma unroll
  for (int l = 0; l < 4; ++l) {
    int f = tid + 256 * l;           // 0..1023
    int oc = f >> 4, h4 = f & 15;    // out-row (=col), 4-row chunk
    int s = ((oc >> 4) & 3) << 2;
    uint2 o = *(const uint2*)(&tT[oc * 68 + ((4 * h4) ^ s)]);  // rows 4h4..4h4+3
    *(uint2*)(oute + (size_t)(c0 + oc) * R + r0 + 4 * h4) = o;
  }
}

// ---------------- GEMM1: 256x256 tile, BK=64, quadrant-aligned 4-phase interleave ----------
// Phase p computes C-quadrant (qm,qn)=(p&1,p>>1). Read sets: A rows bit6==qm,
// B rows bit5==qn. Staging regions == read sets, so each stage targets a region
// whose last LDS-read closed >=1 phase earlier:
//   P0: stage A-odd(kt+1)->nb   (nb's A-odd dead since P1 of kt-1)
//   P1: stage B-high(kt+1)->nb  (dead since P2 of kt-1)
//   P2: stage B-low(kt+2)->cb   (read P0/P1 this tile, closed)
//   P3: stage A-even(kt+2)->cb  (read P0/P2 this tile, closed)
// One counted vmcnt(4) per K-tile at end of P3: oldest 4 halves = tile kt+1's
// regions; 2 halves stay in flight. Register reuse: aev P0->P2, aod P1->P3,
// bl P0->P1, bh P2->P3 => 24 ds_read_b128/wave/K-tile (minimum).
__global__ __launch_bounds__(512, 1) void gemm1_kernel(
    const unsigned short* __restrict__ xbf, const unsigned short* __restrict__ W1t,
    const float* __restrict__ b1, const int* __restrict__ token_list,
    const int* __restrict__ offsets, const int* __restrict__ tile1_e,
    const int* __restrict__ tile1_ms, const int* __restrict__ total_tiles1,
    unsigned short* __restrict__ hbuf) {
  __shared__ __align__(16) unsigned short lds[65536];  // 2 buf x (A 16384 + B 16384 shorts)

  int bx = blockIdx.x;
  int t = (bx & 7) * 9 + (bx >> 3);  // XCD swizzle, 72 = 8*9 (bijective)
  if (t >= *total_tiles1) return;
  int e = tile1_e[t], mstart = tile1_ms[t];
  int base = offsets[e], endp = offsets[e + 1];
  int ntile = blockIdx.y;

  int tid = threadIdx.x;
  int lane = tid & 63, wid = tid >> 6;
  int wm = wid & 1, wn = wid >> 1;      // 2 x 4 waves, wave tile 128x64
  int quad = lane >> 4, l16 = lane & 15;

  int rr = tid >> 3;                    // 0..63
  int g = (tid & 7) ^ (rr & 7);         // staged global k-chunk; slot=tid&7
  int aoff[4];
#pragma unroll
  for (int j = 0; j < 4; ++j) {
    int p = base + mstart + 64 * j + rr;
    p = p < endp ? p : endp - 1;
    aoff[j] = token_list[p] * DDIM + g * 8;
  }
  int brL = rr + (rr & 32);                 // B-low row for load 1 (bit5==0 set)
  int bext = (rr & 32) << 6;                // LDS short-offset of that row vs tid*8
  int boff0 = e * (HDIM * DDIM) + (ntile * 256 + brL) * DDIM + g * 8;

  int swq0 = (quad ^ (l16 & 7)) * 8;        // k-chunks 0..3 (kk=0)
  int swq1 = ((4 + quad) ^ (l16 & 7)) * 8;  // k-chunks 4..7 (kk=1)

  f32x4 acc[8][4];
#pragma unroll
  for (int i = 0; i < 8; ++i)
#pragma unroll
    for (int j = 0; j < 4; ++j) acc[i][j] = (f32x4)0.0f;

  // region stagers: each = 2 gload16 per thread = one 128-row region
  auto stAev = [&](int ko, int bo) {  // A rows {0..63, 128..191}
    unsigned short* L = lds + bo + tid * 8;
    gload16(xbf + aoff[0] + ko, L);
    gload16(xbf + aoff[2] + ko, L + 8192);
  };
  auto stAod = [&](int ko, int bo) {  // A rows {64..127, 192..255}
    unsigned short* L = lds + bo + 4096 + tid * 8;
    gload16(xbf + aoff[1] + ko, L);
    gload16(xbf + aoff[3] + ko, L + 8192);
  };
  auto stBlo = [&](int ko, int bo) {  // B rows with bit5==0
    unsigned short* L = lds + bo + 16384 + bext + tid * 8;
    gload16(W1t + boff0 + ko, L);
    gload16(W1t + boff0 + 128 * DDIM + ko, L + 8192);
  };
  auto stBhi = [&](int ko, int bo) {  // B rows with bit5==1
    unsigned short* L = lds + bo + 16384 + 2048 + bext + tid * 8;
    gload16(W1t + boff0 + 32 * DDIM + ko, L);
    gload16(W1t + boff0 + 160 * DDIM + ko, L + 8192);
  };

  // prologue: tile0 (4 regions) + Blo(1), Aev(1); keep 2 halves in flight
  stAev(0, 0); stBlo(0, 0); stAod(0, 0); stBhi(0, 0);
  stBlo(64, 32768); stAev(64, 32768);
  asm volatile("s_waitcnt vmcnt(4)");
  __builtin_amdgcn_sched_barrier(0);
  __builtin_amdgcn_s_barrier();
  __builtin_amdgcn_sched_barrier(0);

  const int NT = DDIM / 64;  // 16
  for (int kt = 0; kt < NT; ++kt) {
    int cb = (kt & 1) * 32768;
    int nb = cb ^ 32768;
    const unsigned short* Ab = lds + cb + (wm * 128 + l16) * 64;
    const unsigned short* Bb = lds + cb + 16384 + (wn * 64 + l16) * 64;
    short8 aev[4][2], aod[4][2], bl[2][2], bh[2][2];

    // ======== P0 (qm=0,qn=0): read aev(8)+bl(4); stage A-odd(kt+1); acc[0..3][0..1]
#pragma unroll
    for (int fi = 0; fi < 4; ++fi) {
      aev[fi][0] = *(const short8*)(Ab + fi * 1024 + swq0);
      aev[fi][1] = *(const short8*)(Ab + fi * 1024 + swq1);
    }
#pragma unroll
    for (int fj = 0; fj < 2; ++fj) {
      bl[fj][0] = *(const short8*)(Bb + fj * 1024 + swq0);
      bl[fj][1] = *(const short8*)(Bb + fj * 1024 + swq1);
    }
    if (kt + 1 < NT) stAod((kt + 1) * 64, nb);
    __builtin_amdgcn_sched_barrier(0);
    __builtin_amdgcn_s_barrier();
    asm volatile("s_waitcnt lgkmcnt(0)");
    __builtin_amdgcn_sched_barrier(0);
    __builtin_amdgcn_s_setprio(1);
#pragma unroll
    for (int fi = 0; fi < 4; ++fi)
#pragma unroll
      for (int fj = 0; fj < 2; ++fj) {
        acc[fi][fj] = MFMA16(aev[fi][0], bl[fj][0], acc[fi][fj]);
        acc[fi][fj] = MFMA16(aev[fi][1], bl[fj][1], acc[fi][fj]);
      }
    __builtin_amdgcn_s_setprio(0);
    __builtin_amdgcn_sched_barrier(0);
    __builtin_amdgcn_s_barrier();
    __builtin_amdgcn_sched_barrier(0);

    // ======== P1 (qm=1,qn=0): read aod(8); stage B-high(kt+1); acc[4..7][0..1]
#pragma unroll
    for (int fi = 0; fi < 4; ++fi) {
      aod[fi][0] = *(const short8*)(Ab + 4096 + fi * 1024 + swq0);
      aod[fi][1] = *(const short8*)(Ab + 4096 + fi * 1024 + swq1);
    }
    if (kt + 1 < NT) stBhi((kt + 1) * 64, nb);
    __builtin_amdgcn_sched_barrier(0);
    __builtin_amdgcn_s_barrier();
    asm volatile("s_waitcnt lgkmcnt(0)");
    __builtin_amdgcn_sched_barrier(0);
    __builtin_amdgcn_s_setprio(1);
#pragma unroll
    for (int fi = 0; fi < 4; ++fi)
#pragma unroll
      for (int fj = 0; fj < 2; ++fj) {
        acc[4 + fi][fj] = MFMA16(aod[fi][0], bl[fj][0], acc[4 + fi][fj]);
        acc[4 + fi][fj] = MFMA16(aod[fi][1], bl[fj][1], acc[4 + fi][fj]);
      }
    __builtin_amdgcn_s_setprio(0);
    __builtin_amdgcn_sched_barrier(0);
    __builtin_amdgcn_s_barrier();
    __builtin_amdgcn_sched_barrier(0);

    // ======== P2 (qm=0,qn=1): read bh(4); stage B-low(kt+2); acc[0..3][2..3]
#pragma unroll
    for (int fj = 0; fj < 2; ++fj) {
      bh[fj][0] = *(const short8*)(Bb + 2048 + fj * 1024 + swq0);
      bh[fj][1] = *(const short8*)(Bb + 2048 + fj * 1024 + swq1);
    }
    if (kt + 2 < NT) stBlo((kt + 2) * 64, cb);
    __builtin_amdgcn_sched_barrier(0);
    __builtin_amdgcn_s_barrier();
    asm volatile("s_waitcnt lgkmcnt(0)");
    __builtin_amdgcn_sched_barrier(0);
    __builtin_amdgcn_s_setprio(1);
#pragma unroll
    for (int fi = 0; fi < 4; ++fi)
#pragma unroll
      for (int fj = 0; fj < 2; ++fj) {
        acc[fi][2 + fj] = MFMA16(aev[fi][0], bh[fj][0], acc[fi][2 + fj]);
        acc[fi][2 + fj] = MFMA16(aev[fi][1], bh[fj][1], acc[fi][2 + fj]);
      }
    __builtin_amdgcn_s_setprio(0);
    __builtin_amdgcn_sched_barrier(0);
    __builtin_amdgcn_s_barrier();
    __builtin_amdgcn_sched_barrier(0);

    // ======== P3 (qm=1,qn=1): no reads; stage A-even(kt+2); acc[4..7][2..3]; vmcnt
    if (kt + 2 < NT) stAev((kt + 2) * 64, cb);
    __builtin_amdgcn_sched_barrier(0);
    __builtin_amdgcn_s_barrier();
    __builtin_amdgcn_sched_barrier(0);
    __builtin_amdgcn_s_setprio(1);
#pragma unroll
    for (int fi = 0; fi < 4; ++fi)
#pragma unroll
      for (int fj = 0; fj < 2; ++fj) {
        acc[4 + fi][2 + fj] = MFMA16(aod[fi][0], bh[fj][0], acc[4 + fi][2 + fj]);
        acc[4 + fi][2 + fj] = MFMA16(aod[fi][1], bh[fj][1], acc[4 + fi][2 + fj]);
      }
    __builtin_amdgcn_s_setprio(0);
    __builtin_amdgcn_sched_barrier(0);
    if (kt + 2 < NT) {
      asm volatile("s_waitcnt vmcnt(4)");   // tile kt+1 fully resident; 2 halves in flight
    } else if (kt + 1 < NT) {
      asm volatile("s_waitcnt vmcnt(0)");   // tail: drain last tile
    }
    __builtin_amdgcn_sched_barrier(0);
    __builtin_amdgcn_s_barrier();
    __builtin_amdgcn_sched_barrier(0);
  }

  const float* b1e = b1 + (size_t)e * HDIM + ntile * 256;
#pragma unroll
  for (int hm = 0; hm < 2; ++hm) {
#pragma unroll
    for (int fi = 0; fi < 4; ++fi) {
#pragma unroll
      for (int rg = 0; rg < 4; ++rg) {
        int row = wm * 128 + hm * 64 + fi * 16 + quad * 4 + rg;
        int p = base + mstart + row;
        if (p < endp) {
          size_t ob = (size_t)p * HDIM + ntile * 256;
#pragma unroll
          for (int fj = 0; fj < 4; ++fj) {
            int col = wn * 64 + fj * 16 + l16;
            float v = acc[hm * 4 + fi][fj][rg] + b1e[col];
            hbuf[ob + col] = (unsigned short)bf16r(gelu_fast(v));
          }
        }
      }
    }
  }
}

// ---------------- GEMM2: out[tok] = (h @ W2[e] + b2[e]) * top_score ----------------
// BM=192 (wave tile 96x64, 6x4 frags): grid = 96*8 = 768 = exactly 3 blocks/CU.
__global__ __launch_bounds__(256, 3) void gemm2_kernel(
    const unsigned short* __restrict__ hbuf, const unsigned short* __restrict__ W2t,
    const float* __restrict__ b2, const int* __restrict__ token_list,
    const int* __restrict__ offsets, const int* __restrict__ tile2_e,
    const int* __restrict__ tile2_ms, const int* __restrict__ total_tiles2,
    const float* __restrict__ tscore, float* __restrict__ out) {
  __shared__ __align__(16) unsigned short ldsA[192 * 32];
  __shared__ __align__(16) unsigned short ldsB[128 * 32];

  int bx = blockIdx.x;
  int t = (bx & 7) * 12 + (bx >> 3);  // XCD swizzle: 96 = 8*12
  if (t >= *total_tiles2) return;
  int e = tile2_e[t], mstart = tile2_ms[t];
  int base = offsets[e], endp = offsets[e + 1];
  int ntile = blockIdx.y;

  int tid = threadIdx.x;
  int lane = tid & 63, wid = tid >> 6;
  int wr = wid & 1, wc = wid >> 1;
  int quad = lane >> 4, l16 = lane & 15;

  int rowA = tid >> 2, slot = tid & 3;
  int sw = slot ^ (rowA & 3) ^ ((rowA >> 2) & 3);
  int p0 = base + mstart + rowA;
  int pe0 = p0 < endp ? p0 : endp - 1;
  int pe1 = p0 + 64 < endp ? p0 + 64 : endp - 1;
  int pe2 = p0 + 128 < endp ? p0 + 128 : endp - 1;
  int offA0 = pe0 * HDIM + sw * 8;
  int offA1 = pe1 * HDIM + sw * 8;
  int offA2 = pe2 * HDIM + sw * 8;
  int offB0 = e * (HDIM * DDIM) + (ntile * 128 + rowA) * HDIM + sw * 8;
  int offB1 = offB0 + 64 * HDIM;
  unsigned short* la0 = &ldsA[tid * 8];
  unsigned short* la1 = &ldsA[2048 + tid * 8];
  unsigned short* la2 = &ldsA[4096 + tid * 8];
  unsigned short* lb0 = &ldsB[tid * 8];
  unsigned short* lb1 = &ldsB[2048 + tid * 8];

  int swq = (quad ^ (l16 & 3) ^ ((l16 >> 2) & 3)) * 8;

  f32x4 acc[6][4];
#pragma unroll
  for (int i = 0; i < 6; ++i)
#pragma unroll
    for (int j = 0; j < 4; ++j) acc[i][j] = (f32x4)0.0f;

  for (int k0 = 0; k0 < HDIM; k0 += 32) {
    gload16(hbuf + offA0 + k0, la0);
    gload16(hbuf + offA1 + k0, la1);
    gload16(hbuf + offA2 + k0, la2);
    gload16(W2t + offB0 + k0, lb0);
    gload16(W2t + offB1 + k0, lb1);
    __syncthreads();
    short8 af[6], bfr[4];
#pragma unroll
    for (int i = 0; i < 6; ++i)
      af[i] = *(const short8*)(&ldsA[(wr * 96 + 16 * i + l16) * 32 + swq]);
#pragma unroll
    for (int j = 0; j < 4; ++j)
      bfr[j] = *(const short8*)(&ldsB[(wc * 64 + 16 * j + l16) * 32 + swq]);
#pragma unroll
    for (int i = 0; i < 6; ++i)
#pragma unroll
      for (int j = 0; j < 4; ++j)
        acc[i][j] = MFMA16(af[i], bfr[j], acc[i][j]);
    __syncthreads();
  }

  const float* b2e = b2 + (size_t)e * DDIM + ntile * 128;
#pragma unroll
  for (int i = 0; i < 6; ++i) {
#pragma unroll
    for (int r = 0; r < 4; ++r) {
      int row = wr * 96 + 16 * i + quad * 4 + r;
      int p = base + mstart + row;
      if (p < endp) {
        int tok = token_list[p];
        float ts = tscore[tok];
        size_t ob = (size_t)tok * DDIM + ntile * 128;
#pragma unroll
        for (int j = 0; j < 4; ++j) {
          int col = wc * 64 + 16 * j + l16;
          out[ob + col] = (acc[i][j][r] + b2e[col]) * ts;
        }
      }
    }
  }
}

extern "C" void kernel_launch(void* const* d_in, const int* in_sizes, int n_in,
                              void* d_out, int out_size, void* d_ws, size_t ws_size,
                              hipStream_t stream) {
  const float* x  = (const float*)d_in[0];
  const float* Wg = (const float*)d_in[1];
  const float* W1 = (const float*)d_in[2];
  const float* b1 = (const float*)d_in[3];
  const float* W2 = (const float*)d_in[4];
  const float* b2 = (const float*)d_in[5];

  float* out_main = (float*)d_out;
  float* gate_out = out_main + (size_t)BTOK * DDIM;
  float* texp_out = gate_out + (size_t)BTOK * NEXP;
  float* dens_out = texp_out + BTOK;

  char* w = (char*)d_ws;
  size_t off = 0;
  unsigned short* hbuf = (unsigned short*)(w + off); off += (size_t)BTOK * HDIM * 2;  // 134 MB
  unsigned short* xbf  = (unsigned short*)(w + off); off += (size_t)BTOK * DDIM * 2;  // 33.5 MB
  unsigned short* W1t  = (unsigned short*)(w + off); off += (size_t)NEXP * DDIM * HDIM * 2;  // 67 MB
  unsigned short* W2t  = (unsigned short*)(w + off); off += (size_t)NEXP * DDIM * HDIM * 2;  // 67 MB
  float* tscore     = (float*)(w + off); off += (size_t)BTOK * 4;
  int* expert_ws    = (int*)(w + off);   off += (size_t)BTOK * 4;
  int* token_list   = (int*)(w + off);   off += (size_t)BTOK * 4;
  int* counts       = (int*)(w + off);   off += 256;
  int* offsets      = (int*)(w + off);   off += 256;
  int* cursors      = (int*)(w + off);   off += 256;
  int* tile1_e      = (int*)(w + off);   off += 512;
  int* tile1_ms     = (int*)(w + off);   off += 512;
  int* total_tiles1 = (int*)(w + off);   off += 256;
  int* tile2_e      = (int*)(w + off);   off += 512;
  int* tile2_ms     = (int*)(w + off);   off += 512;
  int* total_tiles2 = (int*)(w + off);   off += 256;

  hipLaunchKernelGGL(gate_kernel, dim3(BTOK / 4), dim3(256), 0, stream,
                     x, Wg, gate_out, texp_out, tscore, expert_ws, xbf);
  hipLaunchKernelGGL(plan_kernel, dim3(1), dim3(1024), 0, stream,
                     expert_ws, counts, offsets, cursors,
                     tile1_e, tile1_ms, total_tiles1,
                     tile2_e, tile2_ms, total_tiles2, dens_out);
  hipLaunchKernelGGL(scatter_kernel, dim3(BTOK / 256), dim3(256), 0, stream,
                     expert_ws, cursors, token_list);
  hipLaunchKernelGGL(transpose_cvt_kernel, dim3(HDIM / 64, DDIM / 64, NEXP), dim3(256), 0, stream,
                     W1, W1t, DDIM, HDIM);
  hipLaunchKernelGGL(transpose_cvt_kernel, dim3(DDIM / 64, HDIM / 64, NEXP), dim3(256), 0, stream,
                     W2, W2t, HDIM, DDIM);
  hipLaunchKernelGGL(gemm1_kernel, dim3(MAXT1, HDIM / 256), dim3(512), 0, stream,
                     xbf, W1t, b1, token_list, offsets, tile1_e, tile1_ms, total_tiles1, hbuf);
  hipLaunchKernelGGL(gemm2_kernel, dim3(MAXT2, DDIM / 128), dim3(256), 0, stream,
                     hbuf, W2t, b2, token_list, offsets, tile2_e, tile2_ms, total_tiles2, tscore, out_main);
}